// Round 21
// baseline (190.532 us; speedup 1.0000x reference)
//
#include <hip/hip_runtime.h>
#include <math.h>

typedef _Float16 half8 __attribute__((ext_vector_type(8)));
typedef __fp16   fp16x2 __attribute__((ext_vector_type(2)));  // cvt_pkrtz's return type
typedef float f32x4  __attribute__((ext_vector_type(4)));
typedef float f32x16 __attribute__((ext_vector_type(16)));

// Branchless exact-grade GELU: x*0.5*(1+erf(x/sqrt(2))) with A&S 7.1.26 erf,
// |erf err| <= 1.5e-7 (vs output threshold 2.47e-2).
__device__ __forceinline__ float gelu_f(float v) {
    float y  = v * 0.70710678118654752f;
    float ay = __builtin_fabsf(y);
    float t  = __builtin_amdgcn_rcpf(__builtin_fmaf(0.3275911f, ay, 1.0f));
    float p  = __builtin_fmaf(t, 1.061405429f, -1.453152027f);
    p = __builtin_fmaf(p, t, 1.421413741f);
    p = __builtin_fmaf(p, t, -0.284496736f);
    p = __builtin_fmaf(p, t, 0.254829592f);
    p = p * t;
    float e  = __builtin_amdgcn_exp2f(ay * ay * -1.4426950408889634f);
    float er = __builtin_fmaf(-p, e, 1.0f);        // erf(|y|), saturates to 1
    er = __builtin_copysignf(er, v);               // restore sign
    float hv = 0.5f * v;
    return __builtin_fmaf(hv, er, hv);
}

#define MFMA32(A, B, C) __builtin_amdgcn_mfma_f32_32x32x16_f16((A), (B), (C), 0, 0, 0)

union H8u { half8 h8; fp16x2 h2[4]; };

// 32x32x16 MFMA restructure: one wave owns a 32-row tile end-to-end.
// Rationale (r10-r20 ledger): every config pins at ~880 CU-cycles per 16-row
// tile with NO saturated pipe and NO occupancy sensitivity -> per-tile serial
// overheads (load window, gather window, LDS turnarounds, wtab reads,
// reduce tree) dominate via queueing.  32-row tiles HALVE all per-tile
// overheads per row: 31250 tiles instead of 65536, 16 MFMAs/32rows vs 36,
// and the final 32->1 reduce becomes a matvec MFMA (B = W6 in col 0) --
// no shuffle tree at all.
//
// Layouts: A-frag row = lane&31, k = 16s + 8*(lane>>5) + j (A and B packed
// with the SAME k-map -> k-permutation cancels in the dot product).
// C-layout (m74/m101-verified): col = lane&31, row = (reg&3) + 8*(reg>>2)
// + 4*(lane>>5), reg in [0,16).
__global__ __launch_bounds__(512, 4) void mlp_mfma_kernel(
    const float* __restrict__ x,
    const float* __restrict__ alpha,
    const float* __restrict__ beta,
    const float* __restrict__ gamma,
    const float* __restrict__ gscal,
    const float* __restrict__ W1, const float* __restrict__ b1,
    const float* __restrict__ W2, const float* __restrict__ b2,
    const float* __restrict__ Wres, const float* __restrict__ bres,
    const float* __restrict__ W6, const float* __restrict__ b6,
    float* __restrict__ out, int B)
{
    const int lane  = threadIdx.x & 63;
    const int wid   = threadIdx.x >> 6;   // 0..7
    const int row32 = lane & 31;          // batch-row within tile / output col
    const int half  = lane >> 5;          // k-group half (0/1)

    // Weight-fragment table: f = t*5+s (W1, f 0..9), 10+s (W2, f 10..13),
    // 14+s (Wres, f 14..15), 16+s (W6 matvec col-0, f 16..17).
    // 18 frags x 64 lanes x 16B = 18432 B.
    __shared__ __align__(16) _Float16 wtab[18 * 512];
    // per-wave activation staging
    __shared__ __align__(16) _Float16 h1buf[8][32 * 72]; // 4608 B/wave
    __shared__ __align__(16) _Float16 h2buf[8][32 * 40]; // 2560 B/wave
    _Float16* __restrict__ h1b = h1buf[wid];
    _Float16* __restrict__ h2b = h2buf[wid];

    // ---- build weight tables once (wave 0) ----
    if (wid == 0) {
        // W1: [64,73].  frag(t,s): value = W1[32t+row32][k], k = 16s+8half+j,
        // gamma folded for k in [3,23), zero for k >= 73.
        #pragma unroll
        for (int t = 0; t < 2; ++t)
            #pragma unroll
            for (int s = 0; s < 5; ++s)
                #pragma unroll
                for (int j = 0; j < 8; ++j) {
                    int k  = 16 * s + 8 * half + j;
                    int kc = k < 73 ? k : 72;            // clamp: no OOB load
                    float v = W1[(32 * t + row32) * 73 + kc];
                    int gc = k < 3 ? 3 : (k > 22 ? 22 : k);
                    float gv = gamma[gc];
                    if (k >= 3 && k < 23) v *= gv;       // gamma fold
                    wtab[(t * 5 + s) * 512 + lane * 8 + j] =
                        (k < 73) ? (_Float16)v : (_Float16)0.f;
                }
        // W2: [32,64].  k = 16s+8half+j < 64.
        #pragma unroll
        for (int s = 0; s < 4; ++s)
            #pragma unroll
            for (int j = 0; j < 8; ++j)
                wtab[(10 + s) * 512 + lane * 8 + j] =
                    (_Float16)W2[row32 * 64 + 16 * s + 8 * half + j];
        // Wres: [32,32].  k = 16s+8half+j < 32.
        #pragma unroll
        for (int s = 0; s < 2; ++s)
            #pragma unroll
            for (int j = 0; j < 8; ++j)
                wtab[(14 + s) * 512 + lane * 8 + j] =
                    (_Float16)Wres[row32 * 32 + 16 * s + 8 * half + j];
        // W6 matvec: B[k][col] = W6[k] for col 0 only (out[row] = D[row][0]).
        #pragma unroll
        for (int s = 0; s < 2; ++s)
            #pragma unroll
            for (int j = 0; j < 8; ++j) {
                float v = W6[16 * s + 8 * half + j];
                wtab[(16 + s) * 512 + lane * 8 + j] =
                    (row32 == 0) ? (_Float16)v : (_Float16)0.f;
            }
    }

    // biases in registers
    float b1f[2];
    b1f[0] = b1[row32];
    b1f[1] = b1[32 + row32];
    const float b2f = b2[row32];
    const float brf = bres[row32];
    const float b6g = b6[0] + gscal[0];

    __syncthreads();   // wtab visible to all waves

    const _Float16* wt = wtab + lane * 8;   // shared vaddr; frag f at +f*512

    const int ntiles = B >> 5;      // 31250 tiles of 32 rows
    const int totw   = gridDim.x * 8;
    for (int tile = blockIdx.x * 8 + wid; tile < ntiles; tile += totw) {
        const int R0 = tile << 5;
        const float* __restrict__ xr = x + (size_t)(R0 + row32) * 73;

        // ---- x loads: 5 k-chunks of 8 (k = 16s + 8half + j) ----
        float xv0[8], xv1[8], xv2[8], xv3[8], xv4[8];
        #pragma unroll
        for (int j = 0; j < 8; ++j) xv0[j] = xr[8 * half + j];
        #pragma unroll
        for (int j = 0; j < 8; ++j) xv1[j] = xr[16 + 8 * half + j];
        #pragma unroll
        for (int j = 0; j < 8; ++j) xv2[j] = xr[32 + 8 * half + j];
        #pragma unroll
        for (int j = 0; j < 8; ++j) xv3[j] = xr[48 + 8 * half + j];
        #pragma unroll
        for (int j = 0; j < 8; ++j) {
            int k = 64 + 8 * half + j;
            float v = xr[k < 73 ? k : 72];   // clamp; zero-weight kills pad
            xv4[j] = (k < 73) ? v : 0.f;
        }

        // embed gathers: half==0 lanes own k=0,1 for their row
        float xa = 0.f, xb = 0.f;
        if (half == 0) {
            xa = alpha[(int)xv0[0]];
            xb = beta[(int)xv0[1]];
        }

        // ---- pack A-frags ----
        H8u a0u, a1u, a2u, a3u, a4u;
        #pragma unroll
        for (int j = 0; j < 4; ++j) {
            a0u.h2[j] = __builtin_amdgcn_cvt_pkrtz(xv0[2 * j], xv0[2 * j + 1]);
            a1u.h2[j] = __builtin_amdgcn_cvt_pkrtz(xv1[2 * j], xv1[2 * j + 1]);
            a2u.h2[j] = __builtin_amdgcn_cvt_pkrtz(xv2[2 * j], xv2[2 * j + 1]);
            a3u.h2[j] = __builtin_amdgcn_cvt_pkrtz(xv3[2 * j], xv3[2 * j + 1]);
            a4u.h2[j] = __builtin_amdgcn_cvt_pkrtz(xv4[2 * j], xv4[2 * j + 1]);
        }
        {
            fp16x2 we = __builtin_amdgcn_cvt_pkrtz(xa, xb);
            if (half == 0) a0u.h2[0] = we;   // embed cols 0/1
        }

        // ---- layer 1: 73->64, two 32-col tiles.  s=1..4 first, s=0 last
        //      (covers the gather chain) ----
        f32x16 acc0, acc1;
        #pragma unroll
        for (int r = 0; r < 16; ++r) { acc0[r] = b1f[0]; acc1[r] = b1f[1]; }
        acc0 = MFMA32(a1u.h8, *reinterpret_cast<const half8*>(wt + (0 * 5 + 1) * 512), acc0);
        acc1 = MFMA32(a1u.h8, *reinterpret_cast<const half8*>(wt + (1 * 5 + 1) * 512), acc1);
        acc0 = MFMA32(a2u.h8, *reinterpret_cast<const half8*>(wt + (0 * 5 + 2) * 512), acc0);
        acc1 = MFMA32(a2u.h8, *reinterpret_cast<const half8*>(wt + (1 * 5 + 2) * 512), acc1);
        acc0 = MFMA32(a3u.h8, *reinterpret_cast<const half8*>(wt + (0 * 5 + 3) * 512), acc0);
        acc1 = MFMA32(a3u.h8, *reinterpret_cast<const half8*>(wt + (1 * 5 + 3) * 512), acc1);
        acc0 = MFMA32(a4u.h8, *reinterpret_cast<const half8*>(wt + (0 * 5 + 4) * 512), acc0);
        acc1 = MFMA32(a4u.h8, *reinterpret_cast<const half8*>(wt + (1 * 5 + 4) * 512), acc1);
        acc0 = MFMA32(a0u.h8, *reinterpret_cast<const half8*>(wt + (0 * 5 + 0) * 512), acc0);
        acc1 = MFMA32(a0u.h8, *reinterpret_cast<const half8*>(wt + (1 * 5 + 0) * 512), acc1);

        // GELU -> h1 (row = (r&3)+8*(r>>2)+4*half, col = 32t+row32, pitch 72)
        #pragma unroll
        for (int r = 0; r < 16; ++r) {
            int row = (r & 3) + 8 * (r >> 2) + 4 * half;
            h1b[row * 72 + row32]      = (_Float16)gelu_f(acc0[r]);
            h1b[row * 72 + 32 + row32] = (_Float16)gelu_f(acc1[r]);
        }

        asm volatile("s_waitcnt lgkmcnt(0)" ::: "memory");

        // ---- layer 2: 64->32 (A from h1, conflict-free b128 reads) ----
        f32x16 ac2;
        #pragma unroll
        for (int r = 0; r < 16; ++r) ac2[r] = b2f;
        #pragma unroll
        for (int s = 0; s < 4; ++s) {
            half8 a = *reinterpret_cast<const half8*>(&h1b[row32 * 72 + 16 * s + 8 * half]);
            ac2 = MFMA32(a, *reinterpret_cast<const half8*>(wt + (10 + s) * 512), ac2);
        }
        float h2c[16];
        #pragma unroll
        for (int r = 0; r < 16; ++r) h2c[r] = gelu_f(ac2[r]);

        // h2 to LDS (pitch 40)
        #pragma unroll
        for (int r = 0; r < 16; ++r) {
            int row = (r & 3) + 8 * (r >> 2) + 4 * half;
            h2b[row * 40 + row32] = (_Float16)h2c[r];
        }

        asm volatile("s_waitcnt lgkmcnt(0)" ::: "memory");

        // ---- residual layer: C-init = bres + h2 (matching C slots) ----
        f32x16 acr;
        #pragma unroll
        for (int r = 0; r < 16; ++r) acr[r] = brf + h2c[r];
        #pragma unroll
        for (int s = 0; s < 2; ++s) {
            half8 a = *reinterpret_cast<const half8*>(&h2b[row32 * 40 + 16 * s + 8 * half]);
            acr = MFMA32(a, *reinterpret_cast<const half8*>(wt + (14 + s) * 512), acr);
        }

        // final GELU -> h2 (overwrite; reads above completed in-order)
        #pragma unroll
        for (int r = 0; r < 16; ++r) {
            int row = (r & 3) + 8 * (r >> 2) + 4 * half;
            h2b[row * 40 + row32] = (_Float16)gelu_f(acr[r]);
        }

        asm volatile("s_waitcnt lgkmcnt(0)" ::: "memory");

        // ---- final 32->1 as matvec MFMA: D[row][0] = sum_k h3[row][k]*W6[k] ----
        f32x16 acf;
        #pragma unroll
        for (int r = 0; r < 16; ++r) acf[r] = 0.f;
        #pragma unroll
        for (int s = 0; s < 2; ++s) {
            half8 a = *reinterpret_cast<const half8*>(&h2b[row32 * 40 + 16 * s + 8 * half]);
            acf = MFMA32(a, *reinterpret_cast<const half8*>(wt + (16 + s) * 512), acf);
        }
        if (row32 == 0) {
            // col 0 lanes (0 and 32) hold 16 rows each: row = (r&3)+8q+4half
            #pragma unroll
            for (int q = 0; q < 4; ++q) {
                f32x4 o = { acf[4 * q + 0] + b6g, acf[4 * q + 1] + b6g,
                            acf[4 * q + 2] + b6g, acf[4 * q + 3] + b6g };
                *reinterpret_cast<f32x4*>(out + R0 + 8 * q + 4 * half) = o;
            }
        }
    }
}

extern "C" void kernel_launch(void* const* d_in, const int* in_sizes, int n_in,
                              void* d_out, int out_size, void* d_ws, size_t ws_size,
                              hipStream_t stream) {
    const float* x     = (const float*)d_in[0];
    const float* alpha = (const float*)d_in[1];
    const float* beta  = (const float*)d_in[2];
    const float* gamma = (const float*)d_in[3];
    const float* g     = (const float*)d_in[4];
    const float* W1    = (const float*)d_in[5];
    const float* b1    = (const float*)d_in[6];
    const float* W2    = (const float*)d_in[7];
    const float* b2    = (const float*)d_in[8];
    const float* Wres  = (const float*)d_in[9];
    const float* bres  = (const float*)d_in[10];
    const float* W6    = (const float*)d_in[11];
    const float* b6    = (const float*)d_in[12];
    float* out = (float*)d_out;

    int B = out_size;          // 1e6 rows; divisible by 32
    // 512 blocks x 512 threads: LDS 75776 B/block -> 2 blocks/CU, 16 waves/CU
    // (4/SIMD -- the proven-sufficient regime).  31250 tiles / 4096 waves.
    int nblocks = 512;
    mlp_mfma_kernel<<<nblocks, 512, 0, stream>>>(x, alpha, beta, gamma, g,
                                                 W1, b1, W2, b2, Wres, bres,
                                                 W6, b6, out, B);
}

// Round 22
// 97.090 us; speedup vs baseline: 1.9624x; 1.9624x over previous
//
#include <hip/hip_runtime.h>
#include <math.h>

typedef _Float16 half8 __attribute__((ext_vector_type(8)));
typedef __fp16   fp16x2 __attribute__((ext_vector_type(2)));  // cvt_pkrtz's return type
typedef float f32x4 __attribute__((ext_vector_type(4)));

// Branchless exact-grade GELU: x*0.5*(1+erf(x/sqrt(2))) with A&S 7.1.26 erf,
// |erf err| <= 1.5e-7 (vs output threshold 2.47e-2).
__device__ __forceinline__ float gelu_f(float v) {
    float y  = v * 0.70710678118654752f;
    float ay = __builtin_fabsf(y);
    float t  = __builtin_amdgcn_rcpf(__builtin_fmaf(0.3275911f, ay, 1.0f));
    float p  = __builtin_fmaf(t, 1.061405429f, -1.453152027f);
    p = __builtin_fmaf(p, t, 1.421413741f);
    p = __builtin_fmaf(p, t, -0.284496736f);
    p = __builtin_fmaf(p, t, 0.254829592f);
    p = p * t;
    float e  = __builtin_amdgcn_exp2f(ay * ay * -1.4426950408889634f);
    float er = __builtin_fmaf(-p, e, 1.0f);        // erf(|y|), saturates to 1
    er = __builtin_copysignf(er, v);               // restore sign
    float hv = 0.5f * v;
    return __builtin_fmaf(hv, er, hv);
}

#define MFMA16(A, B, C) __builtin_amdgcn_mfma_f32_16x16x32_f16((A), (B), (C), 0, 0, 0)

// Async global->LDS DMA, width 16 (global_load_lds_dwordx4).  Per-lane global
// src; LDS dest = wave-uniform base + lane*16 (hardware-implicit).
#define GLOAD_LDS16(gsrc, ldst)                                              \
    __builtin_amdgcn_global_load_lds(                                        \
        (const __attribute__((address_space(1))) void*)(gsrc),               \
        (__attribute__((address_space(3))) void*)(ldst), 16, 0, 0)

// One wave owns a 16-row tile end-to-end.  fp16 MFMA, fp32 accum.
// A-frag: row = lane&15, k = 32*s + 8*(lane>>4) + j.  C-layout (m89):
// col = lane&15, row = 4*(lane>>4) + reg.
//
// r22 thesis: per-wave tile latency is 14.5K cyc while issue is only ~1.6K
// (90% stall), and every REGISTER-based prefetch failed to compiler behavior
// (r7 sunk / r8 spilled / r12 order-pinned).  global_load_lds is the async
// mechanism immune to all three: no live registers (can't spill), a side-
// effecting intrinsic (can't sink), tracked by vmcnt (crosses the lgkmcnt
// fences untouched).  Schedule: [vmcnt(0): staged tile ready] -> xv reads
// from LDS -> [lgkmcnt(0): reads retired] -> issue 5 DMAs for tile+1 into
// the SAME buffer -> rest of the body (~2000+ cyc) covers the ~900-cyc HBM
// window.  Body otherwise identical to r14 (96.77us champion); h2 overlays
// h1 (r19-proven) to fit 2 blocks/CU.
__global__ __launch_bounds__(512, 4) void mlp_mfma_kernel(
    const float* __restrict__ x,
    const float* __restrict__ alpha,
    const float* __restrict__ beta,
    const float* __restrict__ gamma,
    const float* __restrict__ gscal,
    const float* __restrict__ W1, const float* __restrict__ b1,
    const float* __restrict__ W2, const float* __restrict__ b2,
    const float* __restrict__ Wres, const float* __restrict__ bres,
    const float* __restrict__ W6, const float* __restrict__ b6,
    float* __restrict__ out, int B)
{
    const int lane = threadIdx.x & 63;
    const int wid  = threadIdx.x >> 6;   // 0..7
    const int c    = lane & 15;   // col (N) index / A-row index
    const int g    = lane >> 4;   // k-group 0..3

    // Weight-fragment table (block-shared): frags 0..11 = W1[t*3+s],
    // 12..15 = W2[12+t*2+s], 16..17 = Wres[16+t].  18 frags x 64 lanes x 16B.
    __shared__ __align__(16) _Float16 wtab[18 * 512];
    // per-wave fp32 x staging (16 rows x 73 floats = 4672 B, 16B-aligned,
    // written ONLY by the async DMA -- must be packed/contiguous)
    __shared__ __align__(16) float xstage[8][16 * 73];
    // per-wave activation staging; h2 (16x40) overlays the head of h1 (16x72)
    __shared__ __align__(16) _Float16 h1buf[8][16 * 72];
    float*     xs  = xstage[wid];
    _Float16*  h1b = h1buf[wid];         // NOT restrict: h1/h2 regions alias

    // ---- build weight tables once (wave 0) ----
    if (wid == 0) {
        float gm[8];
        #pragma unroll
        for (int j = 0; j < 8; ++j) {
            int k  = 8 * g + j;
            int kc = k < 3 ? 3 : (k > 22 ? 22 : k);     // clamp: safe load
            float gv = gamma[kc];
            gm[j] = (k >= 3 && k < 23) ? gv : 1.0f;
        }
        #pragma unroll
        for (int t = 0; t < 4; ++t)
            #pragma unroll
            for (int s = 0; s < 3; ++s)
                #pragma unroll
                for (int j = 0; j < 8; ++j) {
                    int k  = 32 * s + 8 * g + j;
                    int kc = k < 73 ? k : 72;           // clamp: no OOB load
                    float v = W1[(16 * t + c) * 73 + kc];
                    if (s == 0) v *= gm[j];             // gamma folded into s=0
                    wtab[(t * 3 + s) * 512 + lane * 8 + j] =
                        (k < 73) ? (_Float16)v : (_Float16)0.f;
                }
        #pragma unroll
        for (int t = 0; t < 2; ++t)
            #pragma unroll
            for (int s = 0; s < 2; ++s)
                #pragma unroll
                for (int j = 0; j < 8; ++j)
                    wtab[(12 + t * 2 + s) * 512 + lane * 8 + j] =
                        (_Float16)W2[(16 * t + c) * 64 + 32 * s + 8 * g + j];
        #pragma unroll
        for (int t = 0; t < 2; ++t)
            #pragma unroll
            for (int j = 0; j < 8; ++j)
                wtab[(16 + t) * 512 + lane * 8 + j] =
                    (_Float16)Wres[(16 * t + c) * 32 + 8 * g + j];
    }

    // biases / final weights stay in registers (10 regs)
    float b1f[4], b2f[2], brf[2], w6f[2];
    #pragma unroll
    for (int t = 0; t < 4; ++t) b1f[t] = b1[16 * t + c];
    #pragma unroll
    for (int t = 0; t < 2; ++t) { b2f[t] = b2[16 * t + c]; brf[t] = bres[16 * t + c]; w6f[t] = W6[16 * t + c]; }
    const float b6g = b6[0] + gscal[0];

    __syncthreads();   // wtab visible to all waves

    const _Float16* wt = wtab + lane * 8;   // shared vaddr; frag f at +f*512

    const int ntiles = B >> 4;
    const int totw   = gridDim.x * 8;
    const int tile0  = blockIdx.x * 8 + wid;   // < ntiles (4096 waves << 65536)

    // ---- prologue: async-stage the first tile (4672 B = 4x1024 + 576) ----
    {
        const char* src = (const char*)(x + (size_t)(tile0 << 4) * 73);
        char* dst = (char*)xs;
        #pragma unroll
        for (int q = 0; q < 4; ++q)
            GLOAD_LDS16(src + q * 1024 + lane * 16, dst + q * 1024);
        if (lane < 36)
            GLOAD_LDS16(src + 4096 + lane * 16, dst + 4096);
    }

    for (int tile = tile0; tile < ntiles; tile += totw) {
        const int R0 = tile << 4;

        // staged x for THIS tile is ready once the DMAs drain
        asm volatile("s_waitcnt vmcnt(0)" ::: "memory");

        // ---- xv reads from staged fp32 (row c at float offset c*73) ----
        const float* xrow = xs + c * 73;
        float xv0[8], xv1[8], xv2[8];
        #pragma unroll
        for (int j = 0; j < 8; ++j) xv0[j] = xrow[8 * g + j];
        #pragma unroll
        for (int j = 0; j < 8; ++j) xv1[j] = xrow[32 + 8 * g + j];
        #pragma unroll
        for (int j = 0; j < 8; ++j) {
            int k  = 64 + 8 * g + j;
            int kc = k < 73 ? k : 72;         // clamp in-row; zero below
            float v = xrow[kc];
            xv2[j] = (k < 73) ? v : 0.f;
        }

        // embed gathers (g==0 lanes own cols 0/1); consumed by the LAST
        // k-step's MFMAs -- latency covered by k1/k2 phases
        float xa = 0.f, xb = 0.f;
        if (g == 0) {
            xa = alpha[(int)xv0[0]];
            xb = beta[(int)xv0[1]];
        }

        // xv values are in registers; drain the reads, then overwrite-stage
        // the NEXT tile into the same buffer (async, drains at next loop top)
        asm volatile("s_waitcnt lgkmcnt(0)" ::: "memory");
        {
            const int nt = tile + totw;
            if (nt < ntiles) {
                const char* src = (const char*)(x + (size_t)(nt << 4) * 73);
                char* dst = (char*)xs;
                #pragma unroll
                for (int q = 0; q < 4; ++q)
                    GLOAD_LDS16(src + q * 1024 + lane * 16, dst + q * 1024);
                if (lane < 36)
                    GLOAD_LDS16(src + 4096 + lane * 16, dst + 4096);
            }
        }

        // ---- W1 frags from LDS (re-read each tile) ----
        half8 w1f[4][3];
        #pragma unroll
        for (int t = 0; t < 4; ++t)
            #pragma unroll
            for (int s = 0; s < 3; ++s)
                w1f[t][s] = *reinterpret_cast<const half8*>(wt + (t * 3 + s) * 512);

        // ---- layer 1: 73->64.  k-steps 1,2 first (no gather dep) ----
        union H8 { half8 h8; fp16x2 h2[4]; };
        H8 a1u, a2u;
        #pragma unroll
        for (int j = 0; j < 4; ++j) {
            a1u.h2[j] = __builtin_amdgcn_cvt_pkrtz(xv1[2 * j], xv1[2 * j + 1]);
            a2u.h2[j] = __builtin_amdgcn_cvt_pkrtz(xv2[2 * j], xv2[2 * j + 1]);
        }
        f32x4 acc[4];
        #pragma unroll
        for (int t = 0; t < 4; ++t) { f32x4 z = { b1f[t], b1f[t], b1f[t], b1f[t] }; acc[t] = z; }
        #pragma unroll
        for (int t = 0; t < 4; ++t) acc[t] = MFMA16(a1u.h8, w1f[t][1], acc[t]);
        #pragma unroll
        for (int t = 0; t < 4; ++t) acc[t] = MFMA16(a2u.h8, w1f[t][2], acc[t]);

        // k-step 0 last: gamma pre-folded; cols 0/1 replaced by embeds
        H8 a0u;
        #pragma unroll
        for (int j = 0; j < 4; ++j)
            a0u.h2[j] = __builtin_amdgcn_cvt_pkrtz(xv0[2 * j], xv0[2 * j + 1]);
        {
            fp16x2 we = __builtin_amdgcn_cvt_pkrtz(xa, xb);
            if (g == 0) a0u.h2[0] = we;
        }
        #pragma unroll
        for (int t = 0; t < 4; ++t) acc[t] = MFMA16(a0u.h8, w1f[t][0], acc[t]);

        // GELU -> h1 to LDS (row = 4g+r, col = 16t+c, stride 72)
        #pragma unroll
        for (int t = 0; t < 4; ++t)
            #pragma unroll
            for (int r = 0; r < 4; ++r)
                h1b[(4 * g + r) * 72 + 16 * t + c] = (_Float16)gelu_f(acc[t][r]);

        asm volatile("s_waitcnt lgkmcnt(0)" ::: "memory");

        // ---- layer 2: 64->32 ----
        half8 w2f[2][2];
        #pragma unroll
        for (int t = 0; t < 2; ++t)
            #pragma unroll
            for (int s = 0; s < 2; ++s)
                w2f[t][s] = *reinterpret_cast<const half8*>(wt + (12 + t * 2 + s) * 512);

        half8 a2f0 = *reinterpret_cast<const half8*>(&h1b[c * 72 + 8 * g]);
        half8 a2f1 = *reinterpret_cast<const half8*>(&h1b[c * 72 + 32 + 8 * g]);
        f32x4 ac2[2];
        #pragma unroll
        for (int t = 0; t < 2; ++t) {
            f32x4 z = { b2f[t], b2f[t], b2f[t], b2f[t] };
            z = MFMA16(a2f0, w2f[t][0], z);
            ac2[t] = MFMA16(a2f1, w2f[t][1], z);
        }
        float h2c[2][4];
        #pragma unroll
        for (int t = 0; t < 2; ++t)
            #pragma unroll
            for (int r = 0; r < 4; ++r)
                h2c[t][r] = gelu_f(ac2[t][r]);

        // h2 to LDS -- OVERLAID on h1 (stride 40); h1's b128 reads above are
        // complete (results already fed MFMAs); per-wave DS is in-order.
        #pragma unroll
        for (int t = 0; t < 2; ++t)
            #pragma unroll
            for (int r = 0; r < 4; ++r)
                h1b[(4 * g + r) * 40 + 16 * t + c] = (_Float16)h2c[t][r];

        asm volatile("s_waitcnt lgkmcnt(0)" ::: "memory");

        // ---- residual layer: C-init = bres + h2 (matching C-layout slots) ----
        half8 wrf[2];
        #pragma unroll
        for (int t = 0; t < 2; ++t)
            wrf[t] = *reinterpret_cast<const half8*>(wt + (16 + t) * 512);

        half8 arf = *reinterpret_cast<const half8*>(&h1b[c * 40 + 8 * g]);
        f32x4 acr[2];
        #pragma unroll
        for (int t = 0; t < 2; ++t) {
            f32x4 z = { brf[t] + h2c[t][0], brf[t] + h2c[t][1],
                        brf[t] + h2c[t][2], brf[t] + h2c[t][3] };
            acr[t] = MFMA16(arf, wrf[t], z);
        }

        // ---- final 32->1: per-lane partial, butterfly-reduce over c ----
        f32x4 p;
        #pragma unroll
        for (int r = 0; r < 4; ++r)
            p[r] = gelu_f(acr[0][r]) * w6f[0] + gelu_f(acr[1][r]) * w6f[1];
        #pragma unroll
        for (int m = 1; m < 16; m <<= 1) {
            #pragma unroll
            for (int r = 0; r < 4; ++r) p[r] += __shfl_xor(p[r], m, 64);
        }
        if (c == 0) {
            f32x4 o = { p[0] + b6g, p[1] + b6g, p[2] + b6g, p[3] + b6g };
            *reinterpret_cast<f32x4*>(out + R0 + 4 * g) = o;  // rows R0+4g..+3
        }
    }
}

extern "C" void kernel_launch(void* const* d_in, const int* in_sizes, int n_in,
                              void* d_out, int out_size, void* d_ws, size_t ws_size,
                              hipStream_t stream) {
    const float* x     = (const float*)d_in[0];
    const float* alpha = (const float*)d_in[1];
    const float* beta  = (const float*)d_in[2];
    const float* gamma = (const float*)d_in[3];
    const float* g     = (const float*)d_in[4];
    const float* W1    = (const float*)d_in[5];
    const float* b1    = (const float*)d_in[6];
    const float* W2    = (const float*)d_in[7];
    const float* b2    = (const float*)d_in[8];
    const float* Wres  = (const float*)d_in[9];
    const float* bres  = (const float*)d_in[10];
    const float* W6    = (const float*)d_in[11];
    const float* b6    = (const float*)d_in[12];
    float* out = (float*)d_out;

    int B = out_size;          // 1e6 rows; divisible by 16
    // 512 blocks x 512 threads: LDS 74240 B/block -> 2 blocks/CU, 16 waves/CU
    // (4/SIMD, the r14 regime).  16 tiles/wave.
    int nblocks = 512;
    mlp_mfma_kernel<<<nblocks, 512, 0, stream>>>(x, alpha, beta, gamma, g,
                                                 W1, b1, W2, b2, Wres, bres,
                                                 W6, b6, out, B);
}